// Round 15
// baseline (637.544 us; speedup 1.0000x reference)
//
#include <hip/hip_runtime.h>
#include <hip/hip_fp16.h>
#include <math.h>

#define NN 50000
#define EE 800000
#define INDIM 10
#define EMB 32
#define HID 128
#define NLAYERS 3
#define BN_EPS 1e-5f

#define NBIN 196                              // bins of 256 nodes (c >> 8)
#define BCAP 4608                             // max edges per bin (λ=4082, +8σ)
#define CHUNK 2048                            // edges per k_bin block

__device__ __forceinline__ int clampN(int v) {
    return v < 0 ? 0 : (v >= NN ? NN - 1 : v);
}

// ---------------- graph build: two-phase XCD-local binned sort --------------

__global__ void k_zero(int* __restrict__ gcnt) {
    if (threadIdx.x < NBIN) gcnt[threadIdx.x] = 0;
}

// phase 1: LDS-bin a 2048-edge chunk, flush contiguous runs per bin
__global__ __launch_bounds__(256) void k_bin(const int* __restrict__ ei,
                                             const float* __restrict__ ew,
                                             int* __restrict__ gcnt,
                                             long long* __restrict__ gbin) {
    __shared__ long long pay[CHUNK];          // 16 KB
    __shared__ long long srt[CHUNK];          // 16 KB
    __shared__ unsigned char binb[CHUNK];     // 2 KB
    __shared__ int cnt[NBIN], offs[NBIN + 1], cur[NBIN];
    __shared__ int sc[256];
    int t = threadIdx.x;
    int base = blockIdx.x * CHUNK;
    int m = EE - base; if (m > CHUNK) m = CHUNK; if (m < 0) m = 0;

    for (int i = t; i < NBIN; i += 256) cnt[i] = 0;
    __syncthreads();
    for (int i = t; i < m; i += 256) {
        int e = base + i;
        int r = clampN(ei[e]);
        int c = clampN(ei[EE + e]);
        int b = c >> 8;
        pay[i] = ((long long)(unsigned)__float_as_uint(ew[e]) << 32)
               | (unsigned)((r << 8) | (c & 255));
        binb[i] = (unsigned char)b;
        atomicAdd(&cnt[b], 1);
    }
    __syncthreads();
    int v = (t < NBIN) ? cnt[t] : 0;
    sc[t] = v;
    __syncthreads();
    for (int o = 1; o < 256; o <<= 1) {
        int a = (t >= o) ? sc[t - o] : 0;
        __syncthreads();
        sc[t] += a;
        __syncthreads();
    }
    if (t < NBIN) { offs[t] = sc[t] - v; cur[t] = 0; }
    if (t == NBIN - 1) offs[NBIN] = sc[t];
    __syncthreads();
    for (int i = t; i < m; i += 256) {
        int b = binb[i];
        int pos = atomicAdd(&cur[b], 1);
        srt[offs[b] + pos] = pay[i];
    }
    __syncthreads();
    // flush: wave per bin (strided), contiguous global writes per run
    int w64 = t >> 6, l = t & 63;
    for (int b = w64; b < NBIN; b += 4) {
        int s = offs[b];
        int len = offs[b + 1] - s;
        if (len == 0) continue;
        int gpos = 0;
        if (l == 0) gpos = atomicAdd(&gcnt[b], len);
        gpos = __shfl(gpos, 0, 64);
        for (int k = l; k < len; k += 64) {
            int gp = gpos + k; if (gp >= BCAP) gp = BCAP - 1;   // defensive
            gbin[(size_t)b * BCAP + gp] = srt[s + k];
        }
    }
}

// phase 2: per-bin LDS counting sort -> CSR segments + offs_g/cnt_g
__global__ __launch_bounds__(256) void k_binsort(const long long* __restrict__ gbin,
                                                 const int* __restrict__ gcnt,
                                                 int2* __restrict__ csr,
                                                 int* __restrict__ offs_g,
                                                 int* __restrict__ cnt_g) {
    __shared__ long long buf[BCAP];           // 36.9 KB
    __shared__ int cnt[256], offs[256], cur[256], sc[256];
    int b = blockIdx.x, t = threadIdx.x;
    int m = gcnt[b]; if (m > BCAP) m = BCAP;
    for (int i = t; i < m; i += 256) buf[i] = gbin[(size_t)b * BCAP + i];
    cnt[t] = 0;
    __syncthreads();
    for (int i = t; i < m; i += 256)
        atomicAdd(&cnt[(int)((unsigned)buf[i] & 255u)], 1);
    __syncthreads();
    int v = cnt[t];
    sc[t] = v;
    __syncthreads();
    for (int o = 1; o < 256; o <<= 1) {
        int a = (t >= o) ? sc[t - o] : 0;
        __syncthreads();
        sc[t] += a;
        __syncthreads();
    }
    offs[t] = sc[t] - v;
    cur[t] = 0;
    int n = b * 256 + t;
    if (n < NN) { offs_g[n] = b * BCAP + offs[t]; cnt_g[n] = v; }
    __syncthreads();
    // placement: scattered 8B stores but single-block (= single-XCD) region
    for (int i = t; i < m; i += 256) {
        long long p = buf[i];
        unsigned lo = (unsigned)p;
        int cl = lo & 255u;
        int src = lo >> 8;
        int pos = atomicAdd(&cur[cl], 1);
        csr[(size_t)b * BCAP + offs[cl] + pos] =
            make_int2(src, (int)(p >> 32));
    }
}

// wave per node: deg = 1 + sum(segment raw ew) -> dinv = rsqrt(deg)
__global__ __launch_bounds__(256) void k_deg(const int2* __restrict__ csr,
                                             const int* __restrict__ offs_g,
                                             const int* __restrict__ cnt_g,
                                             float* __restrict__ dinv) {
    int n = blockIdx.x * 4 + (threadIdx.x >> 6);
    int l = threadIdx.x & 63;
    if (n >= NN) return;
    int m = cnt_g[n]; if (m > 256) m = 256;
    const int2* seg = &csr[offs_g[n]];
    float s = 0.f;
    for (int i = l; i < m; i += 64) s += __int_as_float(seg[i].y);
    #pragma unroll
    for (int o = 32; o; o >>= 1) s += __shfl_xor(s, o, 64);
    if (l == 0) dinv[n] = rsqrtf(1.0f + s);       // deg >= 1 always
}

// transpose conv_W[L][c][k] -> Wt[L][k][c]
__global__ void k_transpose(const float* __restrict__ W, float* __restrict__ Wt) {
    int idx = blockIdx.x * blockDim.x + threadIdx.x;
    if (idx < NLAYERS * HID * HID) {
        int L = idx >> 14;
        int rem = idx & 16383;
        int k = rem >> 7, c = rem & 127;
        Wt[idx] = W[L * 16384 + c * 128 + k];
    }
}

// transpose comb_W[c][k] ([128][64]) -> Wct[k][c] ([64][128])
__global__ void k_tcomb(const float* __restrict__ W, float* __restrict__ Wct) {
    int idx = blockIdx.x * blockDim.x + threadIdx.x;
    if (idx < HID * 2 * EMB) {
        int k = idx >> 7, c = idx & 127;          // idx = k*128 + c
        Wct[idx] = W[c * (2 * EMB) + k];
    }
}

// ---------------- prologue: h = relu([emb, x@ftW.T+ftb] @ combW.T + combb) --

__global__ __launch_bounds__(256) void k_init_h(
        const float* __restrict__ x, const float* __restrict__ emb,
        const float* __restrict__ ftW, const float* __restrict__ ftb,
        const float* __restrict__ Wct, const float* __restrict__ combb,
        float* __restrict__ h) {
    __shared__ float csh[64 * 68];                // 17.4 KB, stride 68
    __shared__ float xsh[64 * INDIM];             // 2.5 KB
    int t = threadIdx.x;
    int n0 = blockIdx.x * 64;

    for (int s = t; s < 64 * INDIM; s += 256) {
        int j = s / INDIM, q = s - j * INDIM;
        float xv = (n0 + j < NN) ? x[(n0 + j) * INDIM + q] : 0.f;
        unsigned bits = __float_as_uint(xv) & 0x7fffffffu;
        if (bits > 0x7f800000u) xv = 0.f;
        xsh[s] = xv;
    }
    #pragma unroll
    for (int i = 0; i < 8; ++i) {
        int s = i * 256 + t;                      // 0..2047
        int j = s >> 5, k = s & 31;
        csh[j * 68 + k] = (n0 + j < NN) ? emb[(n0 + j) * EMB + k] : 0.f;
    }
    __syncthreads();
    #pragma unroll
    for (int i = 0; i < 8; ++i) {
        int s = i * 256 + t;                      // 0..2047
        int j = s >> 5, kk = s & 31;
        float acc = ftb[kk];
        #pragma unroll
        for (int q = 0; q < INDIM; ++q)
            acc = fmaf(ftW[kk * INDIM + q], xsh[j * INDIM + q], acc);
        csh[j * 68 + 32 + kk] = acc;
    }
    __syncthreads();

    int ty = t >> 4, tx = t & 15;
    float acc[4][8];
    #pragma unroll
    for (int i = 0; i < 4; ++i)
        #pragma unroll
        for (int j = 0; j < 8; ++j) acc[i][j] = 0.f;

    for (int k0 = 0; k0 < 64; k0 += 4) {
        float wf[4][8];
        #pragma unroll
        for (int kk = 0; kk < 4; ++kk) {
            float4 a = *(const float4*)&Wct[(k0 + kk) * HID + tx * 8];
            float4 b = *(const float4*)&Wct[(k0 + kk) * HID + tx * 8 + 4];
            wf[kk][0] = a.x; wf[kk][1] = a.y; wf[kk][2] = a.z; wf[kk][3] = a.w;
            wf[kk][4] = b.x; wf[kk][5] = b.y; wf[kk][6] = b.z; wf[kk][7] = b.w;
        }
        float hf[4][4];
        #pragma unroll
        for (int i = 0; i < 4; ++i) {
            float4 hv = *(const float4*)&csh[(ty * 4 + i) * 68 + k0];
            hf[i][0] = hv.x; hf[i][1] = hv.y; hf[i][2] = hv.z; hf[i][3] = hv.w;
        }
        #pragma unroll
        for (int i = 0; i < 4; ++i)
            #pragma unroll
            for (int kk = 0; kk < 4; ++kk)
                #pragma unroll
                for (int j = 0; j < 8; ++j)
                    acc[i][j] = fmaf(hf[i][kk], wf[kk][j], acc[i][j]);
    }
    #pragma unroll
    for (int i = 0; i < 4; ++i) {
        int n = n0 + ty * 4 + i;
        if (n < NN) {
            float b0 = combb[tx * 8],     b1 = combb[tx * 8 + 1];
            float b2 = combb[tx * 8 + 2], b3 = combb[tx * 8 + 3];
            float b4 = combb[tx * 8 + 4], b5 = combb[tx * 8 + 5];
            float b6 = combb[tx * 8 + 6], b7 = combb[tx * 8 + 7];
            *(float4*)&h[(size_t)n * HID + tx * 8] = make_float4(
                fmaxf(acc[i][0] + b0, 0.f), fmaxf(acc[i][1] + b1, 0.f),
                fmaxf(acc[i][2] + b2, 0.f), fmaxf(acc[i][3] + b3, 0.f));
            *(float4*)&h[(size_t)n * HID + tx * 8 + 4] = make_float4(
                fmaxf(acc[i][4] + b4, 0.f), fmaxf(acc[i][5] + b5, 0.f),
                fmaxf(acc[i][6] + b6, 0.f), fmaxf(acc[i][7] + b7, 0.f));
        }
    }
}

// --- per-layer GEMM: xt = dinv[row] * (h @ W.T), fp16 out for cheap gathers -

#define BM 64
__global__ __launch_bounds__(256) void k_gemm(const float* __restrict__ h,
                                              const float* __restrict__ Wt,
                                              const float* __restrict__ dinv,
                                              __half* __restrict__ xt) {
    __shared__ float hsh[BM * 132];               // stride 132: 2-way (free)
    int t = threadIdx.x;
    int row0 = blockIdx.x * BM;
    #pragma unroll
    for (int i = 0; i < 8; ++i) {
        int s = i * 256 + t;                      // float4 index 0..2047
        int r = s >> 5;
        int cc = s & 31;
        float4 v = make_float4(0.f, 0.f, 0.f, 0.f);
        int row = row0 + r;
        if (row < NN) v = *(const float4*)&h[row * HID + cc * 4];
        *(float4*)&hsh[r * 132 + cc * 4] = v;
    }
    __syncthreads();
    int ty = t >> 4, tx = t & 15;
    float acc[4][8];
    #pragma unroll
    for (int i = 0; i < 4; ++i)
        #pragma unroll
        for (int j = 0; j < 8; ++j) acc[i][j] = 0.f;

    for (int k0 = 0; k0 < HID; k0 += 4) {
        float wf[4][8];
        #pragma unroll
        for (int kk = 0; kk < 4; ++kk) {
            float4 a = *(const float4*)&Wt[(k0 + kk) * HID + tx * 8];
            float4 b = *(const float4*)&Wt[(k0 + kk) * HID + tx * 8 + 4];
            wf[kk][0] = a.x; wf[kk][1] = a.y; wf[kk][2] = a.z; wf[kk][3] = a.w;
            wf[kk][4] = b.x; wf[kk][5] = b.y; wf[kk][6] = b.z; wf[kk][7] = b.w;
        }
        float hf[4][4];
        #pragma unroll
        for (int i = 0; i < 4; ++i) {
            float4 hv = *(const float4*)&hsh[(ty * 4 + i) * 132 + k0];
            hf[i][0] = hv.x; hf[i][1] = hv.y; hf[i][2] = hv.z; hf[i][3] = hv.w;
        }
        #pragma unroll
        for (int i = 0; i < 4; ++i)
            #pragma unroll
            for (int kk = 0; kk < 4; ++kk)
                #pragma unroll
                for (int j = 0; j < 8; ++j)
                    acc[i][j] = fmaf(hf[i][kk], wf[kk][j], acc[i][j]);
    }
    #pragma unroll
    for (int i = 0; i < 4; ++i) {
        int row = row0 + ty * 4 + i;
        if (row < NN) {
            float dv = dinv[row];                 // fold D^{-1/2} (src side)
            __half2 p0 = __floats2half2_rn(acc[i][0] * dv, acc[i][1] * dv);
            __half2 p1 = __floats2half2_rn(acc[i][2] * dv, acc[i][3] * dv);
            __half2 p2 = __floats2half2_rn(acc[i][4] * dv, acc[i][5] * dv);
            __half2 p3 = __floats2half2_rn(acc[i][6] * dv, acc[i][7] * dv);
            uint4 u = make_uint4(*(unsigned*)&p0, *(unsigned*)&p1,
                                 *(unsigned*)&p2, *(unsigned*)&p3);
            *(uint4*)&xt[(size_t)row * HID + tx * 8] = u;
        }
    }
}

// ------- aggregation + self-loop + bias + relu + BN + residual (in-place h) -

__global__ __launch_bounds__(256) void k_aggregate(
        const __half* __restrict__ xt, float* __restrict__ h,
        const int* __restrict__ offs_g, const int* __restrict__ cnt_g,
        const int2* __restrict__ csr, const float* __restrict__ dinv,
        const float* __restrict__ bias, const float* __restrict__ gamma,
        const float* __restrict__ beta, const float* __restrict__ mean,
        const float* __restrict__ var) {
    int n = blockIdx.x * 4 + (threadIdx.x >> 6);
    int l = threadIdx.x & 63;
    if (n >= NN) return;
    const __half2* xt2 = (const __half2*)xt;      // row = 64 half2
    int m = cnt_g[n]; if (m > 256) m = 256;
    const int2* seg = &csr[offs_g[n]];
    float2 accA = make_float2(0.f, 0.f);
    float2 accB = make_float2(0.f, 0.f);
    int i = 0;
    for (; i + 7 < m; i += 8) {                   // 8 gathers in flight
        int2 p_[8];
        #pragma unroll
        for (int q = 0; q < 8; ++q) p_[q] = seg[i + q];
        __half2 r_[8];
        #pragma unroll
        for (int q = 0; q < 8; ++q) r_[q] = xt2[(size_t)p_[q].x * 64 + l];
        #pragma unroll
        for (int q = 0; q < 8; ++q) {
            float wq = __int_as_float(p_[q].y);
            float2 v = __half22float2(r_[q]);
            if (q & 1) { accB.x = fmaf(v.x, wq, accB.x); accB.y = fmaf(v.y, wq, accB.y); }
            else       { accA.x = fmaf(v.x, wq, accA.x); accA.y = fmaf(v.y, wq, accA.y); }
        }
    }
    for (; i < m; ++i) {
        int2 p = seg[i];
        float wgt = __int_as_float(p.y);
        float2 v = __half22float2(xt2[(size_t)p.x * 64 + l]);
        accA.x = fmaf(v.x, wgt, accA.x); accA.y = fmaf(v.y, wgt, accA.y);
    }
    float dn = dinv[n];
    float2 vs = __half22float2(xt2[(size_t)n * 64 + l]);  // self: + xt'[n]
    float ax = (accA.x + accB.x + vs.x) * dn;
    float ay = (accA.y + accB.y + vs.y) * dn;

    int c0 = 2 * l, c1 = c0 + 1;
    float v0 = fmaxf(ax + bias[c0], 0.f);
    float v1 = fmaxf(ay + bias[c1], 0.f);
    v0 = (v0 - mean[c0]) * rsqrtf(var[c0] + BN_EPS) * gamma[c0] + beta[c0];
    v1 = (v1 - mean[c1]) * rsqrtf(var[c1] + BN_EPS) * gamma[c1] + beta[c1];
    float2 hv = *(const float2*)&h[n * HID + c0];
    float2 outv = make_float2(v0 + hv.x, v1 + hv.y);
    *(float2*)&h[n * HID + c0] = outv;
}

// ---------------- final: out = clip(h @ linW.T + linb) ----------------------

__global__ __launch_bounds__(256) void k_final(const float* __restrict__ h,
                                               const float* __restrict__ linW,
                                               const float* __restrict__ linb,
                                               float* __restrict__ out) {
    int n = blockIdx.x * 4 + (threadIdx.x >> 6);
    int l = threadIdx.x & 63;
    if (n >= NN) return;
    const float2* h2 = (const float2*)h;
    const float2* w2 = (const float2*)linW;
    float2 hv = h2[(size_t)n * 64 + l];
    float2 wv = w2[l];
    float s = hv.x * wv.x + hv.y * wv.y;
    #pragma unroll
    for (int off = 32; off; off >>= 1) s += __shfl_xor(s, off, 64);
    if (l == 0) {
        float o = s + linb[0];
        o = fminf(fmaxf(o, -10.f), 10.f);
        out[n] = o;
    }
}

// ---------------- launch ----------------------------------------------------

extern "C" void kernel_launch(void* const* d_in, const int* in_sizes, int n_in,
                              void* d_out, int out_size, void* d_ws, size_t ws_size,
                              hipStream_t stream) {
    const float* x     = (const float*)d_in[0];
    const int*   ei    = (const int*)d_in[1];     // int32: harness narrows int64
    const float* ew    = (const float*)d_in[2];
    const float* emb   = (const float*)d_in[3];
    const float* ftW   = (const float*)d_in[4];
    const float* ftb   = (const float*)d_in[5];
    const float* combW = (const float*)d_in[6];
    const float* combb = (const float*)d_in[7];
    const float* convW = (const float*)d_in[8];
    const float* convb = (const float*)d_in[9];
    const float* gamma = (const float*)d_in[10];
    const float* beta  = (const float*)d_in[11];
    const float* mean  = (const float*)d_in[12];
    const float* var   = (const float*)d_in[13];
    const float* linW  = (const float*)d_in[14];
    const float* linb  = (const float*)d_in[15];
    float* out = (float*)d_out;

    char* ws = (char*)d_ws;
    size_t off = 0;
    auto alloc = [&](size_t bytes) {
        void* p = ws + off;
        off = (off + bytes + 255) & ~(size_t)255;
        return p;
    };
    float*     h      = (float*)alloc((size_t)NN * HID * 4);
    __half*    xt     = (__half*)alloc((size_t)NN * HID * 2);
    float*     dinv   = (float*)alloc((size_t)NN * 4);
    int*       offs_g = (int*)alloc((size_t)NN * 4);
    int*       cnt_g  = (int*)alloc((size_t)NN * 4);
    long long* gbin   = (long long*)alloc((size_t)NBIN * BCAP * 8); // 7.2 MB
    int*       gcnt   = (int*)alloc((size_t)NBIN * 4);
    int2*      csr    = (int2*)alloc((size_t)NBIN * BCAP * 8);      // 7.2 MB
    float*     Wt     = (float*)alloc((size_t)NLAYERS * HID * HID * 4);
    float*     Wct    = (float*)alloc((size_t)HID * 2 * EMB * 4);

    const int NODE4 = (NN + 3) / 4;          // 12500
    const int IHB = (NN + 63) / 64;          // 782
    const int BINB = (EE + CHUNK - 1) / CHUNK; // 391

    k_zero<<<1, 256, 0, stream>>>(gcnt);
    k_bin<<<BINB, 256, 0, stream>>>(ei, ew, gcnt, gbin);
    k_binsort<<<NBIN, 256, 0, stream>>>(gbin, gcnt, csr, offs_g, cnt_g);
    k_deg<<<NODE4, 256, 0, stream>>>(csr, offs_g, cnt_g, dinv);
    k_tcomb<<<(HID * 2 * EMB + 255) / 256, 256, 0, stream>>>(combW, Wct);
    k_init_h<<<IHB, 256, 0, stream>>>(x, emb, ftW, ftb, Wct, combb, h);
    k_transpose<<<(NLAYERS * HID * HID + 255) / 256, 256, 0, stream>>>(convW, Wt);
    for (int L = 0; L < NLAYERS; ++L) {
        k_gemm<<<(NN + BM - 1) / BM, 256, 0, stream>>>(h, Wt + L * HID * HID, dinv, xt);
        k_aggregate<<<NODE4, 256, 0, stream>>>(xt, h, offs_g, cnt_g, csr, dinv,
                                               convb + L * HID, gamma, beta, mean, var);
    }
    k_final<<<NODE4, 256, 0, stream>>>(h, linW, linb, out);
}

// Round 16
// 374.341 us; speedup vs baseline: 1.7031x; 1.7031x over previous
//
#include <hip/hip_runtime.h>
#include <hip/hip_fp16.h>
#include <math.h>

#define NN 50000
#define EE 800000
#define INDIM 10
#define EMB 32
#define HID 128
#define NLAYERS 3
#define BN_EPS 1e-5f
#define CAP 64                                // padded CSR slots per node

__device__ __forceinline__ int clampN(int v) {
    return v < 0 ? 0 : (v >= NN ? NN - 1 : v);
}

// ---------------- setup kernels (graph structure, once per launch) ----------

__global__ void k_init(int* __restrict__ cursor) {
    int i = blockIdx.x * blockDim.x + threadIdx.x;
    if (i < NN) cursor[i] = 0;
}

// single-pass build: scatter (src, raw ew) into padded CSR; cursor -> counts
__global__ void k_fill(const int* __restrict__ ei,
                       const float* __restrict__ ew,
                       int* __restrict__ cursor, int2* __restrict__ csr) {
    int e = blockIdx.x * blockDim.x + threadIdx.x;
    if (e < EE) {
        int r = clampN(ei[e]);
        int c = clampN(ei[EE + e]);
        int pos = atomicAdd(&cursor[c], 1);
        if (pos >= CAP) pos = CAP - 1;            // defensive (P ~ 1e-18)
        long long v = ((long long)(unsigned)__float_as_uint(ew[e]) << 32)
                    | (unsigned)r;                // low 32 = src, high 32 = w
        __builtin_nontemporal_store(v, (long long*)&csr[(size_t)c * CAP + pos]);
    }
}

// wave per node: deg = 1 + sum(segment raw ew) -> dinv = rsqrt(deg)
__global__ __launch_bounds__(256) void k_deg(const int2* __restrict__ csr,
                                             const int* __restrict__ cnt,
                                             float* __restrict__ dinv) {
    int n = blockIdx.x * 4 + (threadIdx.x >> 6);
    int l = threadIdx.x & 63;
    if (n >= NN) return;
    int m = cnt[n]; if (m > CAP) m = CAP;
    const int2* seg = &csr[(size_t)n * CAP];
    float s = 0.f;
    for (int i = l; i < m; i += 64) s += __int_as_float(seg[i].y);
    #pragma unroll
    for (int o = 32; o; o >>= 1) s += __shfl_xor(s, o, 64);
    if (l == 0) dinv[n] = rsqrtf(1.0f + s);       // deg >= 1 always
}

// transpose conv_W[L][c][k] -> Wt[L][k][c]
__global__ void k_transpose(const float* __restrict__ W, float* __restrict__ Wt) {
    int idx = blockIdx.x * blockDim.x + threadIdx.x;
    if (idx < NLAYERS * HID * HID) {
        int L = idx >> 14;
        int rem = idx & 16383;
        int k = rem >> 7, c = rem & 127;
        Wt[idx] = W[L * 16384 + c * 128 + k];
    }
}

// transpose comb_W[c][k] ([128][64]) -> Wct[k][c] ([64][128])
__global__ void k_tcomb(const float* __restrict__ W, float* __restrict__ Wct) {
    int idx = blockIdx.x * blockDim.x + threadIdx.x;
    if (idx < HID * 2 * EMB) {
        int k = idx >> 7, c = idx & 127;          // idx = k*128 + c
        Wct[idx] = W[c * (2 * EMB) + k];
    }
}

// ---------------- prologue: h = relu([emb, x@ftW.T+ftb] @ combW.T + combb) --

__global__ __launch_bounds__(256) void k_init_h(
        const float* __restrict__ x, const float* __restrict__ emb,
        const float* __restrict__ ftW, const float* __restrict__ ftb,
        const float* __restrict__ Wct, const float* __restrict__ combb,
        float* __restrict__ h) {
    __shared__ float csh[64 * 68];                // 17.4 KB, stride 68
    __shared__ float xsh[64 * INDIM];             // 2.5 KB
    int t = threadIdx.x;
    int n0 = blockIdx.x * 64;

    for (int s = t; s < 64 * INDIM; s += 256) {
        int j = s / INDIM, q = s - j * INDIM;
        float xv = (n0 + j < NN) ? x[(n0 + j) * INDIM + q] : 0.f;
        unsigned bits = __float_as_uint(xv) & 0x7fffffffu;
        if (bits > 0x7f800000u) xv = 0.f;
        xsh[s] = xv;
    }
    #pragma unroll
    for (int i = 0; i < 8; ++i) {
        int s = i * 256 + t;                      // 0..2047
        int j = s >> 5, k = s & 31;
        csh[j * 68 + k] = (n0 + j < NN) ? emb[(n0 + j) * EMB + k] : 0.f;
    }
    __syncthreads();
    #pragma unroll
    for (int i = 0; i < 8; ++i) {
        int s = i * 256 + t;                      // 0..2047
        int j = s >> 5, kk = s & 31;
        float acc = ftb[kk];
        #pragma unroll
        for (int q = 0; q < INDIM; ++q)
            acc = fmaf(ftW[kk * INDIM + q], xsh[j * INDIM + q], acc);
        csh[j * 68 + 32 + kk] = acc;
    }
    __syncthreads();

    int ty = t >> 4, tx = t & 15;
    float acc[4][8];
    #pragma unroll
    for (int i = 0; i < 4; ++i)
        #pragma unroll
        for (int j = 0; j < 8; ++j) acc[i][j] = 0.f;

    for (int k0 = 0; k0 < 64; k0 += 4) {
        float wf[4][8];
        #pragma unroll
        for (int kk = 0; kk < 4; ++kk) {
            float4 a = *(const float4*)&Wct[(k0 + kk) * HID + tx * 8];
            float4 b = *(const float4*)&Wct[(k0 + kk) * HID + tx * 8 + 4];
            wf[kk][0] = a.x; wf[kk][1] = a.y; wf[kk][2] = a.z; wf[kk][3] = a.w;
            wf[kk][4] = b.x; wf[kk][5] = b.y; wf[kk][6] = b.z; wf[kk][7] = b.w;
        }
        float hf[4][4];
        #pragma unroll
        for (int i = 0; i < 4; ++i) {
            float4 hv = *(const float4*)&csh[(ty * 4 + i) * 68 + k0];
            hf[i][0] = hv.x; hf[i][1] = hv.y; hf[i][2] = hv.z; hf[i][3] = hv.w;
        }
        #pragma unroll
        for (int i = 0; i < 4; ++i)
            #pragma unroll
            for (int kk = 0; kk < 4; ++kk)
                #pragma unroll
                for (int j = 0; j < 8; ++j)
                    acc[i][j] = fmaf(hf[i][kk], wf[kk][j], acc[i][j]);
    }
    #pragma unroll
    for (int i = 0; i < 4; ++i) {
        int n = n0 + ty * 4 + i;
        if (n < NN) {
            float b0 = combb[tx * 8],     b1 = combb[tx * 8 + 1];
            float b2 = combb[tx * 8 + 2], b3 = combb[tx * 8 + 3];
            float b4 = combb[tx * 8 + 4], b5 = combb[tx * 8 + 5];
            float b6 = combb[tx * 8 + 6], b7 = combb[tx * 8 + 7];
            *(float4*)&h[(size_t)n * HID + tx * 8] = make_float4(
                fmaxf(acc[i][0] + b0, 0.f), fmaxf(acc[i][1] + b1, 0.f),
                fmaxf(acc[i][2] + b2, 0.f), fmaxf(acc[i][3] + b3, 0.f));
            *(float4*)&h[(size_t)n * HID + tx * 8 + 4] = make_float4(
                fmaxf(acc[i][4] + b4, 0.f), fmaxf(acc[i][5] + b5, 0.f),
                fmaxf(acc[i][6] + b6, 0.f), fmaxf(acc[i][7] + b7, 0.f));
        }
    }
}

// --- per-layer GEMM: xt = dinv[row] * (h @ W.T), fp16 out for cheap gathers -

#define BM 64
__global__ __launch_bounds__(256) void k_gemm(const float* __restrict__ h,
                                              const float* __restrict__ Wt,
                                              const float* __restrict__ dinv,
                                              __half* __restrict__ xt) {
    __shared__ float hsh[BM * 132];               // stride 132: 2-way (free)
    int t = threadIdx.x;
    int row0 = blockIdx.x * BM;
    #pragma unroll
    for (int i = 0; i < 8; ++i) {
        int s = i * 256 + t;                      // float4 index 0..2047
        int r = s >> 5;
        int cc = s & 31;
        float4 v = make_float4(0.f, 0.f, 0.f, 0.f);
        int row = row0 + r;
        if (row < NN) v = *(const float4*)&h[row * HID + cc * 4];
        *(float4*)&hsh[r * 132 + cc * 4] = v;
    }
    __syncthreads();
    int ty = t >> 4, tx = t & 15;
    float acc[4][8];
    #pragma unroll
    for (int i = 0; i < 4; ++i)
        #pragma unroll
        for (int j = 0; j < 8; ++j) acc[i][j] = 0.f;

    for (int k0 = 0; k0 < HID; k0 += 4) {
        float wf[4][8];
        #pragma unroll
        for (int kk = 0; kk < 4; ++kk) {
            float4 a = *(const float4*)&Wt[(k0 + kk) * HID + tx * 8];
            float4 b = *(const float4*)&Wt[(k0 + kk) * HID + tx * 8 + 4];
            wf[kk][0] = a.x; wf[kk][1] = a.y; wf[kk][2] = a.z; wf[kk][3] = a.w;
            wf[kk][4] = b.x; wf[kk][5] = b.y; wf[kk][6] = b.z; wf[kk][7] = b.w;
        }
        float hf[4][4];
        #pragma unroll
        for (int i = 0; i < 4; ++i) {
            float4 hv = *(const float4*)&hsh[(ty * 4 + i) * 132 + k0];
            hf[i][0] = hv.x; hf[i][1] = hv.y; hf[i][2] = hv.z; hf[i][3] = hv.w;
        }
        #pragma unroll
        for (int i = 0; i < 4; ++i)
            #pragma unroll
            for (int kk = 0; kk < 4; ++kk)
                #pragma unroll
                for (int j = 0; j < 8; ++j)
                    acc[i][j] = fmaf(hf[i][kk], wf[kk][j], acc[i][j]);
    }
    #pragma unroll
    for (int i = 0; i < 4; ++i) {
        int row = row0 + ty * 4 + i;
        if (row < NN) {
            float dv = dinv[row];                 // fold D^{-1/2} (src side)
            __half2 p0 = __floats2half2_rn(acc[i][0] * dv, acc[i][1] * dv);
            __half2 p1 = __floats2half2_rn(acc[i][2] * dv, acc[i][3] * dv);
            __half2 p2 = __floats2half2_rn(acc[i][4] * dv, acc[i][5] * dv);
            __half2 p3 = __floats2half2_rn(acc[i][6] * dv, acc[i][7] * dv);
            uint4 u = make_uint4(*(unsigned*)&p0, *(unsigned*)&p1,
                                 *(unsigned*)&p2, *(unsigned*)&p3);
            *(uint4*)&xt[(size_t)row * HID + tx * 8] = u;
        }
    }
}

// ------- aggregation + self-loop + bias + relu + BN + residual (in-place h) -
// out[n] = dinv[n]*(sum ew*xt'[src] + xt'[n]),  xt' = dinv-scaled gemm out

__global__ __launch_bounds__(256) void k_aggregate(
        const __half* __restrict__ xt, float* __restrict__ h,
        const int* __restrict__ cnt, const int2* __restrict__ csr,
        const float* __restrict__ dinv,
        const float* __restrict__ bias, const float* __restrict__ gamma,
        const float* __restrict__ beta, const float* __restrict__ mean,
        const float* __restrict__ var) {
    int n = blockIdx.x * 4 + (threadIdx.x >> 6);
    int l = threadIdx.x & 63;
    if (n >= NN) return;
    const __half2* xt2 = (const __half2*)xt;      // row = 64 half2
    const int2* seg = &csr[(size_t)n * CAP];
    int m = cnt[n]; if (m > CAP) m = CAP;
    float2 accA = make_float2(0.f, 0.f);
    float2 accB = make_float2(0.f, 0.f);
    int i = 0;
    for (; i + 7 < m; i += 8) {                   // 8 gathers in flight
        int2 p_[8];
        #pragma unroll
        for (int q = 0; q < 8; ++q) p_[q] = seg[i + q];
        __half2 r_[8];
        #pragma unroll
        for (int q = 0; q < 8; ++q) r_[q] = xt2[(size_t)p_[q].x * 64 + l];
        #pragma unroll
        for (int q = 0; q < 8; ++q) {
            float wq = __int_as_float(p_[q].y);
            float2 v = __half22float2(r_[q]);
            if (q & 1) { accB.x = fmaf(v.x, wq, accB.x); accB.y = fmaf(v.y, wq, accB.y); }
            else       { accA.x = fmaf(v.x, wq, accA.x); accA.y = fmaf(v.y, wq, accA.y); }
        }
    }
    for (; i < m; ++i) {
        int2 p = seg[i];
        float wgt = __int_as_float(p.y);
        float2 v = __half22float2(xt2[(size_t)p.x * 64 + l]);
        accA.x = fmaf(v.x, wgt, accA.x); accA.y = fmaf(v.y, wgt, accA.y);
    }
    float dn = dinv[n];
    float2 vs = __half22float2(xt2[(size_t)n * 64 + l]);  // self: + xt'[n]
    float ax = (accA.x + accB.x + vs.x) * dn;
    float ay = (accA.y + accB.y + vs.y) * dn;

    int c0 = 2 * l, c1 = c0 + 1;
    float v0 = fmaxf(ax + bias[c0], 0.f);
    float v1 = fmaxf(ay + bias[c1], 0.f);
    v0 = (v0 - mean[c0]) * rsqrtf(var[c0] + BN_EPS) * gamma[c0] + beta[c0];
    v1 = (v1 - mean[c1]) * rsqrtf(var[c1] + BN_EPS) * gamma[c1] + beta[c1];
    float2 hv = *(const float2*)&h[n * HID + c0];
    float2 outv = make_float2(v0 + hv.x, v1 + hv.y);
    *(float2*)&h[n * HID + c0] = outv;
}

// ---------------- final: out = clip(h @ linW.T + linb) ----------------------

__global__ __launch_bounds__(256) void k_final(const float* __restrict__ h,
                                               const float* __restrict__ linW,
                                               const float* __restrict__ linb,
                                               float* __restrict__ out) {
    int n = blockIdx.x * 4 + (threadIdx.x >> 6);
    int l = threadIdx.x & 63;
    if (n >= NN) return;
    const float2* h2 = (const float2*)h;
    const float2* w2 = (const float2*)linW;
    float2 hv = h2[(size_t)n * 64 + l];
    float2 wv = w2[l];
    float s = hv.x * wv.x + hv.y * wv.y;
    #pragma unroll
    for (int off = 32; off; off >>= 1) s += __shfl_xor(s, off, 64);
    if (l == 0) {
        float o = s + linb[0];
        o = fminf(fmaxf(o, -10.f), 10.f);
        out[n] = o;
    }
}

// ---------------- launch ----------------------------------------------------

extern "C" void kernel_launch(void* const* d_in, const int* in_sizes, int n_in,
                              void* d_out, int out_size, void* d_ws, size_t ws_size,
                              hipStream_t stream) {
    const float* x     = (const float*)d_in[0];
    const int*   ei    = (const int*)d_in[1];     // int32: harness narrows int64
    const float* ew    = (const float*)d_in[2];
    const float* emb   = (const float*)d_in[3];
    const float* ftW   = (const float*)d_in[4];
    const float* ftb   = (const float*)d_in[5];
    const float* combW = (const float*)d_in[6];
    const float* combb = (const float*)d_in[7];
    const float* convW = (const float*)d_in[8];
    const float* convb = (const float*)d_in[9];
    const float* gamma = (const float*)d_in[10];
    const float* beta  = (const float*)d_in[11];
    const float* mean  = (const float*)d_in[12];
    const float* var   = (const float*)d_in[13];
    const float* linW  = (const float*)d_in[14];
    const float* linb  = (const float*)d_in[15];
    float* out = (float*)d_out;

    char* ws = (char*)d_ws;
    size_t off = 0;
    auto alloc = [&](size_t bytes) {
        void* p = ws + off;
        off = (off + bytes + 255) & ~(size_t)255;
        return p;
    };
    float*  h       = (float*)alloc((size_t)NN * HID * 4);
    __half* xt      = (__half*)alloc((size_t)NN * HID * 2);
    float*  dinv    = (float*)alloc((size_t)NN * 4);
    int*    cnt     = (int*)alloc((size_t)NN * 4);       // cursor -> counts
    int2*   csr     = (int2*)alloc((size_t)NN * CAP * 8);// padded CSR, 25.6 MB
    float*  Wt      = (float*)alloc((size_t)NLAYERS * HID * HID * 4);
    float*  Wct     = (float*)alloc((size_t)HID * 2 * EMB * 4);

    const int NBK = (NN + 255) / 256;        // 196
    const int EB = (EE + 255) / 256;         // 3125
    const int NODE4 = (NN + 3) / 4;          // 12500
    const int IHB = (NN + 63) / 64;          // 782

    k_init<<<NBK, 256, 0, stream>>>(cnt);
    k_fill<<<EB, 256, 0, stream>>>(ei, ew, cnt, csr);
    k_deg<<<NODE4, 256, 0, stream>>>(csr, cnt, dinv);
    k_tcomb<<<(HID * 2 * EMB + 255) / 256, 256, 0, stream>>>(combW, Wct);
    k_init_h<<<IHB, 256, 0, stream>>>(x, emb, ftW, ftb, Wct, combb, h);
    k_transpose<<<(NLAYERS * HID * HID + 255) / 256, 256, 0, stream>>>(convW, Wt);
    for (int L = 0; L < NLAYERS; ++L) {
        k_gemm<<<(NN + BM - 1) / BM, 256, 0, stream>>>(h, Wt + L * HID * HID, dinv, xt);
        k_aggregate<<<NODE4, 256, 0, stream>>>(xt, h, cnt, csr, dinv,
                                               convb + L * HID, gamma, beta, mean, var);
    }
    k_final<<<NODE4, 256, 0, stream>>>(h, linW, linb, out);
}

// Round 17
// 354.725 us; speedup vs baseline: 1.7973x; 1.0553x over previous
//
#include <hip/hip_runtime.h>
#include <hip/hip_fp16.h>
#include <math.h>

#define NN 50000
#define EE 800000
#define INDIM 10
#define EMB 32
#define HID 128
#define NLAYERS 3
#define BN_EPS 1e-5f
#define CAP 64                                // padded CSR slots per node (4B each)

__device__ __forceinline__ int clampN(int v) {
    return v < 0 ? 0 : (v >= NN ? NN - 1 : v);
}

// ---------------- setup kernels (graph structure, once per launch) ----------

__global__ void k_init(int* __restrict__ cursor) {
    int i = blockIdx.x * blockDim.x + threadIdx.x;
    if (i < NN) cursor[i] = 0;
}

// single-pass build: scatter packed (src:u16 | ew:fp16) into padded CSR
__global__ void k_fill(const int* __restrict__ ei,
                       const float* __restrict__ ew,
                       int* __restrict__ cursor, unsigned* __restrict__ csr) {
    int e = blockIdx.x * blockDim.x + threadIdx.x;
    if (e < EE) {
        int r = clampN(ei[e]);
        int c = clampN(ei[EE + e]);
        int pos = atomicAdd(&cursor[c], 1);
        if (pos >= CAP) pos = CAP - 1;            // defensive (P ~ 1e-11)
        unsigned short hw = __half_as_ushort(__float2half(ew[e]));
        unsigned v = (unsigned)(unsigned short)r | ((unsigned)hw << 16);
        __builtin_nontemporal_store(v, &csr[(size_t)c * CAP + pos]);
    }
}

// wave per node: deg = 1 + sum(segment fp16 ew) -> dinv = rsqrt(deg)
__global__ __launch_bounds__(256) void k_deg(const unsigned* __restrict__ csr,
                                             const int* __restrict__ cnt,
                                             float* __restrict__ dinv) {
    int n = blockIdx.x * 4 + (threadIdx.x >> 6);
    int l = threadIdx.x & 63;
    if (n >= NN) return;
    int m = cnt[n]; if (m > CAP) m = CAP;
    const unsigned* seg = &csr[(size_t)n * CAP];
    float s = 0.f;
    for (int i = l; i < m; i += 64)
        s += __half2float(__ushort_as_half((unsigned short)(seg[i] >> 16)));
    #pragma unroll
    for (int o = 32; o; o >>= 1) s += __shfl_xor(s, o, 64);
    if (l == 0) dinv[n] = rsqrtf(1.0f + s);       // deg >= 1 always
}

// fused weight prep: Wt[L][k][c] = convW[L][c][k];  Wct[k][c] = combW[c][k]
__global__ void k_wprep(const float* __restrict__ convW,
                        const float* __restrict__ combW,
                        float* __restrict__ Wt, float* __restrict__ Wct) {
    int idx = blockIdx.x * blockDim.x + threadIdx.x;
    if (idx < NLAYERS * HID * HID) {
        int L = idx >> 14;
        int rem = idx & 16383;
        int k = rem >> 7, c = rem & 127;
        Wt[idx] = convW[L * 16384 + c * 128 + k];
    } else {
        int j = idx - NLAYERS * HID * HID;
        if (j < HID * 2 * EMB) {
            int k = j >> 7, c = j & 127;          // j = k*128 + c
            Wct[j] = combW[c * (2 * EMB) + k];
        }
    }
}

// ---------------- prologue: h = relu([emb, x@ftW.T+ftb] @ combW.T + combb) --

__global__ __launch_bounds__(256) void k_init_h(
        const float* __restrict__ x, const float* __restrict__ emb,
        const float* __restrict__ ftW, const float* __restrict__ ftb,
        const float* __restrict__ Wct, const float* __restrict__ combb,
        float* __restrict__ h) {
    __shared__ float csh[64 * 68];                // 17.4 KB, stride 68
    __shared__ float xsh[64 * INDIM];             // 2.5 KB
    int t = threadIdx.x;
    int n0 = blockIdx.x * 64;

    for (int s = t; s < 64 * INDIM; s += 256) {
        int j = s / INDIM, q = s - j * INDIM;
        float xv = (n0 + j < NN) ? x[(n0 + j) * INDIM + q] : 0.f;
        unsigned bits = __float_as_uint(xv) & 0x7fffffffu;
        if (bits > 0x7f800000u) xv = 0.f;
        xsh[s] = xv;
    }
    #pragma unroll
    for (int i = 0; i < 8; ++i) {
        int s = i * 256 + t;                      // 0..2047
        int j = s >> 5, k = s & 31;
        csh[j * 68 + k] = (n0 + j < NN) ? emb[(n0 + j) * EMB + k] : 0.f;
    }
    __syncthreads();
    #pragma unroll
    for (int i = 0; i < 8; ++i) {
        int s = i * 256 + t;                      // 0..2047
        int j = s >> 5, kk = s & 31;
        float acc = ftb[kk];
        #pragma unroll
        for (int q = 0; q < INDIM; ++q)
            acc = fmaf(ftW[kk * INDIM + q], xsh[j * INDIM + q], acc);
        csh[j * 68 + 32 + kk] = acc;
    }
    __syncthreads();

    int ty = t >> 4, tx = t & 15;
    float acc[4][8];
    #pragma unroll
    for (int i = 0; i < 4; ++i)
        #pragma unroll
        for (int j = 0; j < 8; ++j) acc[i][j] = 0.f;

    for (int k0 = 0; k0 < 64; k0 += 4) {
        float wf[4][8];
        #pragma unroll
        for (int kk = 0; kk < 4; ++kk) {
            float4 a = *(const float4*)&Wct[(k0 + kk) * HID + tx * 8];
            float4 b = *(const float4*)&Wct[(k0 + kk) * HID + tx * 8 + 4];
            wf[kk][0] = a.x; wf[kk][1] = a.y; wf[kk][2] = a.z; wf[kk][3] = a.w;
            wf[kk][4] = b.x; wf[kk][5] = b.y; wf[kk][6] = b.z; wf[kk][7] = b.w;
        }
        float hf[4][4];
        #pragma unroll
        for (int i = 0; i < 4; ++i) {
            float4 hv = *(const float4*)&csh[(ty * 4 + i) * 68 + k0];
            hf[i][0] = hv.x; hf[i][1] = hv.y; hf[i][2] = hv.z; hf[i][3] = hv.w;
        }
        #pragma unroll
        for (int i = 0; i < 4; ++i)
            #pragma unroll
            for (int kk = 0; kk < 4; ++kk)
                #pragma unroll
                for (int j = 0; j < 8; ++j)
                    acc[i][j] = fmaf(hf[i][kk], wf[kk][j], acc[i][j]);
    }
    #pragma unroll
    for (int i = 0; i < 4; ++i) {
        int n = n0 + ty * 4 + i;
        if (n < NN) {
            float b0 = combb[tx * 8],     b1 = combb[tx * 8 + 1];
            float b2 = combb[tx * 8 + 2], b3 = combb[tx * 8 + 3];
            float b4 = combb[tx * 8 + 4], b5 = combb[tx * 8 + 5];
            float b6 = combb[tx * 8 + 6], b7 = combb[tx * 8 + 7];
            *(float4*)&h[(size_t)n * HID + tx * 8] = make_float4(
                fmaxf(acc[i][0] + b0, 0.f), fmaxf(acc[i][1] + b1, 0.f),
                fmaxf(acc[i][2] + b2, 0.f), fmaxf(acc[i][3] + b3, 0.f));
            *(float4*)&h[(size_t)n * HID + tx * 8 + 4] = make_float4(
                fmaxf(acc[i][4] + b4, 0.f), fmaxf(acc[i][5] + b5, 0.f),
                fmaxf(acc[i][6] + b6, 0.f), fmaxf(acc[i][7] + b7, 0.f));
        }
    }
}

// --- per-layer GEMM: xt = dinv[row] * (h @ W.T), fp16 out for cheap gathers -

#define BM 64
__global__ __launch_bounds__(256) void k_gemm(const float* __restrict__ h,
                                              const float* __restrict__ Wt,
                                              const float* __restrict__ dinv,
                                              __half* __restrict__ xt) {
    __shared__ float hsh[BM * 132];               // stride 132: 2-way (free)
    int t = threadIdx.x;
    int row0 = blockIdx.x * BM;
    #pragma unroll
    for (int i = 0; i < 8; ++i) {
        int s = i * 256 + t;                      // float4 index 0..2047
        int r = s >> 5;
        int cc = s & 31;
        float4 v = make_float4(0.f, 0.f, 0.f, 0.f);
        int row = row0 + r;
        if (row < NN) v = *(const float4*)&h[row * HID + cc * 4];
        *(float4*)&hsh[r * 132 + cc * 4] = v;
    }
    __syncthreads();
    int ty = t >> 4, tx = t & 15;
    float acc[4][8];
    #pragma unroll
    for (int i = 0; i < 4; ++i)
        #pragma unroll
        for (int j = 0; j < 8; ++j) acc[i][j] = 0.f;

    for (int k0 = 0; k0 < HID; k0 += 4) {
        float wf[4][8];
        #pragma unroll
        for (int kk = 0; kk < 4; ++kk) {
            float4 a = *(const float4*)&Wt[(k0 + kk) * HID + tx * 8];
            float4 b = *(const float4*)&Wt[(k0 + kk) * HID + tx * 8 + 4];
            wf[kk][0] = a.x; wf[kk][1] = a.y; wf[kk][2] = a.z; wf[kk][3] = a.w;
            wf[kk][4] = b.x; wf[kk][5] = b.y; wf[kk][6] = b.z; wf[kk][7] = b.w;
        }
        float hf[4][4];
        #pragma unroll
        for (int i = 0; i < 4; ++i) {
            float4 hv = *(const float4*)&hsh[(ty * 4 + i) * 132 + k0];
            hf[i][0] = hv.x; hf[i][1] = hv.y; hf[i][2] = hv.z; hf[i][3] = hv.w;
        }
        #pragma unroll
        for (int i = 0; i < 4; ++i)
            #pragma unroll
            for (int kk = 0; kk < 4; ++kk)
                #pragma unroll
                for (int j = 0; j < 8; ++j)
                    acc[i][j] = fmaf(hf[i][kk], wf[kk][j], acc[i][j]);
    }
    #pragma unroll
    for (int i = 0; i < 4; ++i) {
        int row = row0 + ty * 4 + i;
        if (row < NN) {
            float dv = dinv[row];                 // fold D^{-1/2} (src side)
            __half2 p0 = __floats2half2_rn(acc[i][0] * dv, acc[i][1] * dv);
            __half2 p1 = __floats2half2_rn(acc[i][2] * dv, acc[i][3] * dv);
            __half2 p2 = __floats2half2_rn(acc[i][4] * dv, acc[i][5] * dv);
            __half2 p3 = __floats2half2_rn(acc[i][6] * dv, acc[i][7] * dv);
            uint4 u = make_uint4(*(unsigned*)&p0, *(unsigned*)&p1,
                                 *(unsigned*)&p2, *(unsigned*)&p3);
            *(uint4*)&xt[(size_t)row * HID + tx * 8] = u;
        }
    }
}

// ------- aggregation + self-loop + bias + relu + BN + residual (in-place h) -
// out[n] = dinv[n]*(sum ew*xt'[src] + xt'[n]),  xt' = dinv-scaled gemm out

__global__ __launch_bounds__(256) void k_aggregate(
        const __half* __restrict__ xt, float* __restrict__ h,
        const int* __restrict__ cnt, const unsigned* __restrict__ csr,
        const float* __restrict__ dinv,
        const float* __restrict__ bias, const float* __restrict__ gamma,
        const float* __restrict__ beta, const float* __restrict__ mean,
        const float* __restrict__ var) {
    int n = blockIdx.x * 4 + (threadIdx.x >> 6);
    int l = threadIdx.x & 63;
    if (n >= NN) return;
    const __half2* xt2 = (const __half2*)xt;      // row = 64 half2
    const unsigned* seg = &csr[(size_t)n * CAP];
    int m = cnt[n]; if (m > CAP) m = CAP;
    float2 accA = make_float2(0.f, 0.f);
    float2 accB = make_float2(0.f, 0.f);
    int i = 0;
    for (; i + 7 < m; i += 8) {                   // 8 gathers in flight
        unsigned p_[8];
        #pragma unroll
        for (int q = 0; q < 8; ++q) p_[q] = seg[i + q];
        __half2 r_[8];
        #pragma unroll
        for (int q = 0; q < 8; ++q)
            r_[q] = xt2[(size_t)(p_[q] & 0xffffu) * 64 + l];
        #pragma unroll
        for (int q = 0; q < 8; ++q) {
            float wq = __half2float(__ushort_as_half((unsigned short)(p_[q] >> 16)));
            float2 v = __half22float2(r_[q]);
            if (q & 1) { accB.x = fmaf(v.x, wq, accB.x); accB.y = fmaf(v.y, wq, accB.y); }
            else       { accA.x = fmaf(v.x, wq, accA.x); accA.y = fmaf(v.y, wq, accA.y); }
        }
    }
    for (; i < m; ++i) {
        unsigned p = seg[i];
        float wgt = __half2float(__ushort_as_half((unsigned short)(p >> 16)));
        float2 v = __half22float2(xt2[(size_t)(p & 0xffffu) * 64 + l]);
        accA.x = fmaf(v.x, wgt, accA.x); accA.y = fmaf(v.y, wgt, accA.y);
    }
    float dn = dinv[n];
    float2 vs = __half22float2(xt2[(size_t)n * 64 + l]);  // self: + xt'[n]
    float ax = (accA.x + accB.x + vs.x) * dn;
    float ay = (accA.y + accB.y + vs.y) * dn;

    int c0 = 2 * l, c1 = c0 + 1;
    float v0 = fmaxf(ax + bias[c0], 0.f);
    float v1 = fmaxf(ay + bias[c1], 0.f);
    v0 = (v0 - mean[c0]) * rsqrtf(var[c0] + BN_EPS) * gamma[c0] + beta[c0];
    v1 = (v1 - mean[c1]) * rsqrtf(var[c1] + BN_EPS) * gamma[c1] + beta[c1];
    float2 hv = *(const float2*)&h[n * HID + c0];
    float2 outv = make_float2(v0 + hv.x, v1 + hv.y);
    *(float2*)&h[n * HID + c0] = outv;
}

// ---------------- final: out = clip(h @ linW.T + linb) ----------------------

__global__ __launch_bounds__(256) void k_final(const float* __restrict__ h,
                                               const float* __restrict__ linW,
                                               const float* __restrict__ linb,
                                               float* __restrict__ out) {
    int n = blockIdx.x * 4 + (threadIdx.x >> 6);
    int l = threadIdx.x & 63;
    if (n >= NN) return;
    const float2* h2 = (const float2*)h;
    const float2* w2 = (const float2*)linW;
    float2 hv = h2[(size_t)n * 64 + l];
    float2 wv = w2[l];
    float s = hv.x * wv.x + hv.y * wv.y;
    #pragma unroll
    for (int off = 32; off; off >>= 1) s += __shfl_xor(s, off, 64);
    if (l == 0) {
        float o = s + linb[0];
        o = fminf(fmaxf(o, -10.f), 10.f);
        out[n] = o;
    }
}

// ---------------- launch ----------------------------------------------------

extern "C" void kernel_launch(void* const* d_in, const int* in_sizes, int n_in,
                              void* d_out, int out_size, void* d_ws, size_t ws_size,
                              hipStream_t stream) {
    const float* x     = (const float*)d_in[0];
    const int*   ei    = (const int*)d_in[1];     // int32: harness narrows int64
    const float* ew    = (const float*)d_in[2];
    const float* emb   = (const float*)d_in[3];
    const float* ftW   = (const float*)d_in[4];
    const float* ftb   = (const float*)d_in[5];
    const float* combW = (const float*)d_in[6];
    const float* combb = (const float*)d_in[7];
    const float* convW = (const float*)d_in[8];
    const float* convb = (const float*)d_in[9];
    const float* gamma = (const float*)d_in[10];
    const float* beta  = (const float*)d_in[11];
    const float* mean  = (const float*)d_in[12];
    const float* var   = (const float*)d_in[13];
    const float* linW  = (const float*)d_in[14];
    const float* linb  = (const float*)d_in[15];
    float* out = (float*)d_out;

    char* ws = (char*)d_ws;
    size_t off = 0;
    auto alloc = [&](size_t bytes) {
        void* p = ws + off;
        off = (off + bytes + 255) & ~(size_t)255;
        return p;
    };
    float*    h    = (float*)alloc((size_t)NN * HID * 4);
    __half*   xt   = (__half*)alloc((size_t)NN * HID * 2);
    float*    dinv = (float*)alloc((size_t)NN * 4);
    int*      cnt  = (int*)alloc((size_t)NN * 4);        // cursor -> counts
    unsigned* csr  = (unsigned*)alloc((size_t)NN * CAP * 4); // packed CSR, 12.8 MB
    float*    Wt   = (float*)alloc((size_t)NLAYERS * HID * HID * 4);
    float*    Wct  = (float*)alloc((size_t)HID * 2 * EMB * 4);

    const int NBK = (NN + 255) / 256;        // 196
    const int EB = (EE + 255) / 256;         // 3125
    const int NODE4 = (NN + 3) / 4;          // 12500
    const int IHB = (NN + 63) / 64;          // 782
    const int WPB = (NLAYERS * HID * HID + HID * 2 * EMB + 255) / 256;

    k_init<<<NBK, 256, 0, stream>>>(cnt);
    k_fill<<<EB, 256, 0, stream>>>(ei, ew, cnt, csr);
    k_deg<<<NODE4, 256, 0, stream>>>(csr, cnt, dinv);
    k_wprep<<<WPB, 256, 0, stream>>>(convW, combW, Wt, Wct);
    k_init_h<<<IHB, 256, 0, stream>>>(x, emb, ftW, ftb, Wct, combb, h);
    for (int L = 0; L < NLAYERS; ++L) {
        k_gemm<<<(NN + BM - 1) / BM, 256, 0, stream>>>(h, Wt + L * HID * HID, dinv, xt);
        k_aggregate<<<NODE4, 256, 0, stream>>>(xt, h, cnt, csr, dinv,
                                               convb + L * HID, gamma, beta, mean, var);
    }
    k_final<<<NODE4, 256, 0, stream>>>(h, linW, linb, out);
}